// Round 1
// baseline (243.501 us; speedup 1.0000x reference)
//
#include <hip/hip_runtime.h>
#include <hip/hip_bf16.h>

// Problem: fasterRCNN box decode + per-class argmax region pick.
// Inputs (float32): boxes (N,4), box_deltas (N,28), scores (N,7), im_info (3)
// Outputs (float32, concatenated): pred_boxes (N*28), region_g (5), region_l (5)
//
// Stage 1 (fused, memory-bound): one thread per (row,class) pair p = i*7+c.
//   - deltas[p] is an aligned float4 (row stride 112B = 7*16B) -> coalesced
//   - pred[p] float4 store -> coalesced
//   - scores flat index == p -> coalesced
//   - boxes[i]: 7 consecutive lanes share one float4 (L1 broadcast)
//   Per-class argmax (classes 1..6) with exact first-index tie-break:
//   key = (monotone(score) << 32) | (0xFFFFFFFF - i); LDS atomicMax per block
//   (hi-word pre-check to avoid contention), per-block winners to d_ws.
// Stage 2 (tiny): reduce per-block winners, decode idx/score, gather box from
//   pred output, write the two 5-float regions.

#define THRESH_F 0.05f
#define NCLS 7
#define BLOCKS 2048
#define TPB 256

__device__ __forceinline__ unsigned map_float(unsigned bits) {
    // monotone map float bits -> unsigned (order-preserving for all finite floats)
    return (bits & 0x80000000u) ? ~bits : (bits | 0x80000000u);
}

__global__ __launch_bounds__(TPB) void decode_pick_kernel(
    const float4* __restrict__ boxes,
    const float4* __restrict__ deltas,
    const float*  __restrict__ scores,
    const float*  __restrict__ im_info,
    float4*       __restrict__ pred,
    unsigned long long* __restrict__ blockbest,
    int NP)
{
    __shared__ unsigned long long sbest[6];
    const int tid = threadIdx.x;
    if (tid < 6) sbest[tid] = 0ULL;
    __syncthreads();

    const float maxX = im_info[1] - 1.0f;   // W-1 = 999
    const float maxY = im_info[0] - 1.0f;   // H-1 = 599

    const int stride = gridDim.x * blockDim.x;
    for (int p = blockIdx.x * blockDim.x + tid; p < NP; p += stride) {
        const unsigned up = (unsigned)p;
        const unsigned i  = up / 7u;          // compiler magic-mul
        const unsigned c  = up - i * 7u;

        const float4 d = deltas[p];
        const float4 b = boxes[i];

        const float w  = b.z - b.x + 1.0f;
        const float h  = b.w - b.y + 1.0f;
        const float cx = b.x + 0.5f * w;
        const float cy = b.y + 0.5f * h;

        const float pcx = (d.x * 0.1f) * w + cx;
        const float pcy = (d.y * 0.1f) * h + cy;
        const float pw  = __expf(d.z * 0.2f) * w * 0.5f;
        const float ph  = __expf(d.w * 0.2f) * h * 0.5f;

        float4 o;
        o.x = fminf(fmaxf(pcx - pw, 0.0f), maxX);
        o.y = fminf(fmaxf(pcy - ph, 0.0f), maxY);
        o.z = fminf(fmaxf(pcx + pw, 0.0f), maxX);
        o.w = fminf(fmaxf(pcy + ph, 0.0f), maxY);
        pred[p] = o;

        if (c != 0u) {
            const float s = scores[p];
            const float m = (s > THRESH_F) ? s : -1.0f;
            const unsigned mapped = map_float(__float_as_uint(m));
            const unsigned long long key =
                ((unsigned long long)mapped << 32) |
                (unsigned long long)(0xFFFFFFFFu - i);
            const int slot = (int)c - 1;
            // 4B hi-word pre-check (atomic wrt tearing) to skip most LDS atomics
            const unsigned curhi = ((volatile unsigned*)sbest)[slot * 2 + 1];
            if (mapped >= curhi)
                atomicMax(&sbest[slot], key);
        }
    }
    __syncthreads();
    if (tid < 6)
        blockbest[(size_t)blockIdx.x * 6 + tid] = sbest[tid];
}

__global__ __launch_bounds__(TPB) void finalize_kernel(
    const unsigned long long* __restrict__ blockbest,
    int nblocks,
    const float* __restrict__ pred,
    float*       __restrict__ regions)   // d_out + N*28, 10 floats
{
    __shared__ unsigned long long red[TPB];
    __shared__ unsigned long long fin[6];
    const int tid = threadIdx.x;

    for (int slot = 0; slot < 6; ++slot) {
        unsigned long long k = 0ULL;
        for (int j = tid; j < nblocks; j += TPB) {
            unsigned long long v = blockbest[(size_t)j * 6 + slot];
            k = (v > k) ? v : k;
        }
        red[tid] = k;
        __syncthreads();
        for (int off = TPB / 2; off > 0; off >>= 1) {
            if (tid < off) {
                unsigned long long v = red[tid + off];
                if (v > red[tid]) red[tid] = v;
            }
            __syncthreads();
        }
        if (tid == 0) fin[slot] = red[0];
        __syncthreads();
    }

    if (tid == 0) {
        for (int g = 0; g < 2; ++g) {
            float scores_[3];
            unsigned idx_[3];
            float bestScore = -1e30f;
            int bestJ = 0;
            for (int j = 0; j < 3; ++j) {
                const unsigned long long key = fin[g * 3 + j];
                const unsigned hi = (unsigned)(key >> 32);
                const unsigned bits = (hi & 0x80000000u) ? (hi & 0x7FFFFFFFu) : ~hi;
                const float sc = __uint_as_float(bits);
                const unsigned idx = 0xFFFFFFFFu - (unsigned)(key & 0xFFFFFFFFu);
                scores_[j] = sc;
                idx_[j] = idx;
                if (sc > bestScore) { bestScore = sc; bestJ = j; }  // strict > : first-max tie-break
            }
            const int c = g * 3 + bestJ + 1;
            const unsigned i = idx_[bestJ];
            const float* pb = pred + (size_t)i * 28 + (size_t)c * 4;
            float* r = regions + g * 5;
            r[0] = pb[0];
            r[1] = pb[1];
            r[2] = pb[2];
            r[3] = pb[3];
            r[4] = scores_[bestJ];
        }
    }
}

extern "C" void kernel_launch(void* const* d_in, const int* in_sizes, int n_in,
                              void* d_out, int out_size, void* d_ws, size_t ws_size,
                              hipStream_t stream) {
    const float* boxes   = (const float*)d_in[0];
    const float* deltas  = (const float*)d_in[1];
    const float* scores  = (const float*)d_in[2];
    const float* im_info = (const float*)d_in[3];

    const int N  = in_sizes[0] / 4;      // 1,000,000
    const int NP = N * NCLS;             // 7,000,000 (row,class) pairs

    float* out = (float*)d_out;
    float* regions = out + (size_t)N * 4 * NCLS;   // after pred_boxes

    unsigned long long* blockbest = (unsigned long long*)d_ws;  // BLOCKS*6*8 = 96 KB

    decode_pick_kernel<<<BLOCKS, TPB, 0, stream>>>(
        (const float4*)boxes, (const float4*)deltas, scores, im_info,
        (float4*)out, blockbest, NP);

    finalize_kernel<<<1, TPB, 0, stream>>>(blockbest, BLOCKS, out, regions);
}